// Round 1
// baseline (2799.919 us; speedup 1.0000x reference)
//
#include <hip/hip_runtime.h>

// Problem constants (from reference)
#define B_   16
#define OC_  10
#define N_   256
#define O_   2560   // OC_*N_
#define S_   64     // synapses
#define T_   512
#define KS_  48
#define TP_  561    // T + KS + 1
#define TT   24     // time steps register-tiled per thread
#define WROW 72     // LDS row stride (70 needed; 72 keeps float4 alignment)

// ---------------------------------------------------------------------------
// A: transpose weight [2560][64] -> wT [64][2560] so conv loads are coalesced
// ---------------------------------------------------------------------------
__global__ void transpose_w(const float* __restrict__ w, float* __restrict__ wT) {
    int idx = blockIdx.x * 256 + threadIdx.x;          // 0 .. 163839
    if (idx >= O_ * S_) return;
    int o = idx >> 6, i = idx & 63;
    wT[i * O_ + o] = w[idx];
}

// ---------------------------------------------------------------------------
// B: conv.  block = 256 threads <-> 256 consecutive o; grid = (10, B, 24 t-chunks)
// pot layout: [b][t][o]  (o innermost -> coalesced stores, coalesced scan reads)
// Exact-grid two-component accumulation: acc_hi is bit-exact (multiples of 2^-12,
// x in {0,1}, pot < 4096); acc_lo residual ~2^-13 -> total error ~1e-7 rel.
// ---------------------------------------------------------------------------
__global__ __launch_bounds__(256) void conv_kernel(
    const float* __restrict__ x, const float* __restrict__ wT,
    float* __restrict__ pot)
{
    const int b  = blockIdx.y;
    const int t0 = blockIdx.z * TT;
    const int o  = blockIdx.x * 256 + threadIdx.x;

    __shared__ __align__(16) float xsh[S_][WROW];
    // stage x window: xsh[i][m] = x[b,i,t0-48+m], zero outside [0,512)
    for (int idx = threadIdx.x; idx < S_ * WROW; idx += 256) {
        int i = idx / WROW, m = idx - i * WROW;
        int t = t0 - KS_ + m;
        float v = 0.0f;
        if (t >= 0 && t < T_) v = x[(b * S_ + i) * T_ + t];
        xsh[i][m] = v;
    }
    __syncthreads();

    float acch[TT], accl[TT];
#pragma unroll
    for (int tl = 0; tl < TT; ++tl) { acch[tl] = 0.0f; accl[tl] = 0.0f; }

    for (int i = 0; i < S_; ++i) {
        // pull row window into registers (vector LDS reads, broadcast: conflict-free)
        float xw[WROW];
#pragma unroll
        for (int w4 = 0; w4 < WROW / 4; ++w4) {
            const float4 v = *reinterpret_cast<const float4*>(&xsh[i][w4 * 4]);
            xw[w4 * 4 + 0] = v.x; xw[w4 * 4 + 1] = v.y;
            xw[w4 * 4 + 2] = v.z; xw[w4 * 4 + 3] = v.w;
        }
        const float wv = wT[i * O_ + o];
#pragma unroll
        for (int j = 1; j < KS_; ++j) {
            // mirror reference: max(0, min(t/STEP, -(t - w*STEP)/LEAK + w))
            float rise = (float)j * 0.0625f;
            float leak = -((float)j - wv * 16.0f) * 0.03125f + wv;
            float kv   = fmaxf(0.0f, fminf(rise, leak));
            float khi  = rintf(kv * 4096.0f) * 2.44140625e-4f;  // on 2^-12 grid
            float klo  = kv - khi;                               // |klo| <= 2^-13
#pragma unroll
            for (int tl = 0; tl < TT; ++tl) {
                float xv = xw[tl + (KS_ - 1) - j];   // x[b,i,(t0+tl)-1-j]
                acch[tl] = fmaf(xv, khi, acch[tl]);  // exact
                accl[tl] = fmaf(xv, klo, accl[tl]);  // tiny residual
            }
        }
    }
#pragma unroll
    for (int tl = 0; tl < TT; ++tl) {
        int t = t0 + tl;
        if (t < TP_) pot[((size_t)b * TP_ + t) * O_ + o] = acch[tl] + accl[tl];
    }
}

// ---------------------------------------------------------------------------
// C1: per (b,n,t) would-spike + winner (independent of depression state).
// code[(b*TP+t)*N + n] = spike ? winner+1 : 0
// ---------------------------------------------------------------------------
__global__ void scan_prep(const float* __restrict__ pot, unsigned char* __restrict__ code) {
    int idx = blockIdx.x * 256 + threadIdx.x;
    if (idx >= B_ * TP_ * N_) return;
    int n  = idx & (N_ - 1);
    int bt = idx >> 8;                       // b*TP + t
    const float* p = pot + (size_t)bt * O_ + n;
    float best = p[0]; int bo = 0;
#pragma unroll
    for (int oc = 1; oc < OC_; ++oc) {
        float v = p[oc * N_];
        if (v > best) { best = v; bo = oc; } // strict > keeps FIRST max (jnp.argmax)
    }
    // reference: masked = pot + BIAS*THETA; spike = masked > THETA
    code[idx] = ((best + 16.0f) > 32.0f) ? (unsigned char)(bo + 1) : (unsigned char)0;
}

// ---------------------------------------------------------------------------
// C2: sequential walk per (b,n): spike -> emit one-hot, jump 48 (FODEP); else +1.
// ---------------------------------------------------------------------------
__global__ void scan_run(const unsigned char* __restrict__ code, float* __restrict__ out) {
    int idx = blockIdx.x * 256 + threadIdx.x;
    if (idx >= B_ * N_) return;
    int b = idx >> 8, n = idx & 255;
    const unsigned char* c = code + (size_t)b * TP_ * N_ + n;
    int t = 0;
    while (t < TP_) {
        unsigned char v = c[(size_t)t * N_];
        if (v) {
            out[(((size_t)b * OC_ + (v - 1)) * N_ + n) * TP_ + t] = 1.0f;
            t += KS_;
        } else {
            ++t;
        }
    }
}

// ---------------------------------------------------------------------------
extern "C" void kernel_launch(void* const* d_in, const int* in_sizes, int n_in,
                              void* d_out, int out_size, void* d_ws, size_t ws_size,
                              hipStream_t stream) {
    const float* x = (const float*)d_in[0];   // [16][1][64][512] binary
    const float* w = (const float*)d_in[1];   // [2560][64]
    float* out = (float*)d_out;               // [16][10][256][561]

    char* ws = (char*)d_ws;
    size_t pot_bytes  = (size_t)B_ * TP_ * O_ * sizeof(float); // 91,914,240
    size_t code_bytes = (size_t)B_ * TP_ * N_;                 //  2,297,856
    float* pot = (float*)ws;
    unsigned char* code = (unsigned char*)(ws + pot_bytes);
    float* wT = (float*)(ws + pot_bytes + code_bytes);         // 655,360 B; ~95.5 MB total

    hipMemsetAsync(d_out, 0, (size_t)out_size * sizeof(float), stream);
    transpose_w<<<(O_ * S_ + 255) / 256, 256, 0, stream>>>(w, wT);
    conv_kernel<<<dim3(O_ / 256, B_, (TP_ + TT - 1) / TT), 256, 0, stream>>>(x, wT, pot);
    scan_prep<<<(B_ * TP_ * N_ + 255) / 256, 256, 0, stream>>>(pot, code);
    scan_run<<<(B_ * N_ + 255) / 256, 256, 0, stream>>>(code, out);
}

// Round 2
// 508.288 us; speedup vs baseline: 5.5085x; 5.5085x over previous
//
#include <hip/hip_runtime.h>

// Problem constants (from reference)
#define B_   16
#define OC_  10
#define N_   256
#define O_   2560   // OC_*N_
#define S_   64     // synapses
#define T_   512
#define KS_  48
#define TP_  561    // T + KS + 1
#define TT   24     // (fallback conv) time steps per thread
#define WROW 72     // (fallback conv) LDS row stride

// GEMM path constants
#define KTOT  3072          // S_*KS_
#define MROWS 9088          // 71*128 (B_*TP_=8976 padded)
#define MVAL  8976
#define NCOLS 5120          // 2*O_ (digit-interleaved)

// ===========================================================================
// GEMM PATH
// ===========================================================================

// ---------------------------------------------------------------------------
// prep_A: im2col of x -> A[bt][k] fp16, k = i*48+j, A = x[b,i,t'-1-j]
// ---------------------------------------------------------------------------
__global__ void prep_A(const float* __restrict__ x, _Float16* __restrict__ A) {
    int idx = blockIdx.x * 256 + threadIdx.x;
    if (idx >= MROWS * KTOT) return;
    int bt = idx / KTOT;
    int k  = idx - bt * KTOT;
    int i = k / KS_, j = k - i * KS_;
    int b = bt / TP_, t = bt - b * TP_;
    int ts = t - 1 - j;
    float v = 0.0f;
    if (bt < MVAL && ts >= 0 && ts < T_) v = x[((b << 6) + i) * T_ + ts];
    A[idx] = (_Float16)v;
}

// ---------------------------------------------------------------------------
// prep_B: kernel taps -> 22-bit fixed point -> two 11-bit signed digits,
// stored as fp16 (integers <=2048, exact).  Bt[n'=2o+d][k]  (N x K, "B^T").
// ---------------------------------------------------------------------------
__global__ void prep_B(const float* __restrict__ w, _Float16* __restrict__ Bt) {
    int idx = blockIdx.x * 256 + threadIdx.x;  // o*3072 + i*48 + j
    if (idx >= O_ * KTOT) return;
    int o = idx / KTOT;
    int k = idx - o * KTOT;
    int i = k / KS_, j = k - i * KS_;
    float wv = w[(o << 6) + i];
    float rise = (float)j * 0.0625f;
    float leak = -((float)j - wv * 16.0f) * 0.03125f + wv;
    float kv   = fmaxf(0.0f, fminf(rise, leak));     // in [0,1]
    int q  = (int)lrintf(kv * 4194304.0f);           // kv * 2^22 (exact scale)
    int d0 = ((q + 1024) & 2047) - 1024;             // [-1024, 1023]
    int d1 = (q - d0) >> 11;                         // [0, 2048]
    Bt[(size_t)(2 * o) * KTOT + k]     = (_Float16)d0;
    Bt[(size_t)(2 * o + 1) * KTOT + k] = (_Float16)d1;
}

// ---------------------------------------------------------------------------
// gemm: 128x128 tile, BK=32, global_load_lds staging, mfma_f32_16x16x32_f16.
// All accumulators hold exact integers (< 2^24). Epilogue combines digit
// pairs (adjacent columns / adjacent lanes) in double -> fp32 pot[b][t][o].
// ---------------------------------------------------------------------------
using f16x8 = __attribute__((ext_vector_type(8))) _Float16;
using f32x4 = __attribute__((ext_vector_type(4))) float;

__global__ __launch_bounds__(256) void gemm_kernel(
    const _Float16* __restrict__ A,   // [MROWS][KTOT]
    const _Float16* __restrict__ Bt,  // [NCOLS][KTOT]
    float* __restrict__ pot)          // [MVAL][O_]
{
    __shared__ __align__(16) _Float16 Ash[128][32];
    __shared__ __align__(16) _Float16 Bsh[128][32];

    const int tid  = threadIdx.x;
    const int lane = tid & 63;
    const int wave = tid >> 6;
    const int bn = blockIdx.x, bm = blockIdx.y;
    const int row0 = bm * 128;          // A rows (bt)
    const int col0 = bn * 128;          // Bt rows (n')

    const int m_base = (wave >> 1) * 64;
    const int n_base = (wave & 1) * 64;
    const int lrow = lane & 15;
    const int quad = lane >> 4;

    f32x4 acc[4][4];
#pragma unroll
    for (int mi = 0; mi < 4; ++mi)
#pragma unroll
        for (int ni = 0; ni < 4; ++ni)
            acc[mi][ni] = (f32x4){0.f, 0.f, 0.f, 0.f};

    _Float16* AshP = &Ash[0][0];
    _Float16* BshP = &Bsh[0][0];

    for (int kb = 0; kb < KTOT; kb += 32) {
        // stage 128x32 fp16 tiles of A and Bt (8 KB each) via async 16B loads
#pragma unroll
        for (int s = 0; s < 2; ++s) {
            int seg = tid + 256 * s;        // 0..511
            int r = seg >> 2, p = seg & 3;  // row in tile, 16B part
            const _Float16* ga = A  + (size_t)(row0 + r) * KTOT + kb + p * 8;
            const _Float16* gb = Bt + (size_t)(col0 + r) * KTOT + kb + p * 8;
            __builtin_amdgcn_global_load_lds(
                (const __attribute__((address_space(1))) void*)ga,
                (__attribute__((address_space(3))) void*)(AshP + seg * 8),
                16, 0, 0);
            __builtin_amdgcn_global_load_lds(
                (const __attribute__((address_space(1))) void*)gb,
                (__attribute__((address_space(3))) void*)(BshP + seg * 8),
                16, 0, 0);
        }
        __syncthreads();

        f16x8 af[4], bf[4];
#pragma unroll
        for (int mi = 0; mi < 4; ++mi)
            af[mi] = *(const f16x8*)&Ash[m_base + mi * 16 + lrow][quad * 8];
#pragma unroll
        for (int ni = 0; ni < 4; ++ni)
            bf[ni] = *(const f16x8*)&Bsh[n_base + ni * 16 + lrow][quad * 8];

#pragma unroll
        for (int mi = 0; mi < 4; ++mi)
#pragma unroll
            for (int ni = 0; ni < 4; ++ni)
                acc[mi][ni] = __builtin_amdgcn_mfma_f32_16x16x32_f16(
                    af[mi], bf[ni], acc[mi][ni], 0, 0, 0);
        __syncthreads();
    }

    // epilogue: C/D layout col=lane&15, row=quad*4+reg (HW-verified family).
    // n' = col0 + n_base + ni*16 + lrow; digit pairs are adjacent lanes.
#pragma unroll
    for (int mi = 0; mi < 4; ++mi) {
#pragma unroll
        for (int ni = 0; ni < 4; ++ni) {
            f32x4 v = acc[mi][ni];
#pragma unroll
            for (int r = 0; r < 4; ++r) {
                float other = __shfl_xor(v[r], 1);  // partner digit
                if (!(lrow & 1)) {
                    // even lane: a0 = v[r] (d=0), a1 = other (d=1)
                    double pq = ((double)v[r] + 2048.0 * (double)other)
                                * (1.0 / 4194304.0);
                    int bt = row0 + m_base + mi * 16 + quad * 4 + r;
                    int o  = (col0 + n_base + ni * 16 + lrow) >> 1;
                    if (bt < MVAL)
                        pot[(size_t)bt * O_ + o] = (float)pq;
                }
            }
        }
    }
}

// ===========================================================================
// FALLBACK PATH (round-1 direct conv) — used only if ws_size is too small
// ===========================================================================
__global__ void transpose_w(const float* __restrict__ w, float* __restrict__ wT) {
    int idx = blockIdx.x * 256 + threadIdx.x;
    if (idx >= O_ * S_) return;
    int o = idx >> 6, i = idx & 63;
    wT[i * O_ + o] = w[idx];
}

__global__ __launch_bounds__(256) void conv_kernel(
    const float* __restrict__ x, const float* __restrict__ wT,
    float* __restrict__ pot)
{
    const int b  = blockIdx.y;
    const int t0 = blockIdx.z * TT;
    const int o  = blockIdx.x * 256 + threadIdx.x;

    __shared__ __align__(16) float xsh[S_][WROW];
    for (int idx = threadIdx.x; idx < S_ * WROW; idx += 256) {
        int i = idx / WROW, m = idx - i * WROW;
        int t = t0 - KS_ + m;
        float v = 0.0f;
        if (t >= 0 && t < T_) v = x[(b * S_ + i) * T_ + t];
        xsh[i][m] = v;
    }
    __syncthreads();

    float acch[TT], accl[TT];
#pragma unroll
    for (int tl = 0; tl < TT; ++tl) { acch[tl] = 0.0f; accl[tl] = 0.0f; }

    for (int i = 0; i < S_; ++i) {
        float xw[WROW];
#pragma unroll
        for (int w4 = 0; w4 < WROW / 4; ++w4) {
            const float4 v = *reinterpret_cast<const float4*>(&xsh[i][w4 * 4]);
            xw[w4 * 4 + 0] = v.x; xw[w4 * 4 + 1] = v.y;
            xw[w4 * 4 + 2] = v.z; xw[w4 * 4 + 3] = v.w;
        }
        const float wv = wT[i * O_ + o];
#pragma unroll
        for (int j = 1; j < KS_; ++j) {
            float rise = (float)j * 0.0625f;
            float leak = -((float)j - wv * 16.0f) * 0.03125f + wv;
            float kv   = fmaxf(0.0f, fminf(rise, leak));
            float khi  = rintf(kv * 4096.0f) * 2.44140625e-4f;
            float klo  = kv - khi;
#pragma unroll
            for (int tl = 0; tl < TT; ++tl) {
                float xv = xw[tl + (KS_ - 1) - j];
                acch[tl] = fmaf(xv, khi, acch[tl]);
                accl[tl] = fmaf(xv, klo, accl[tl]);
            }
        }
    }
#pragma unroll
    for (int tl = 0; tl < TT; ++tl) {
        int t = t0 + tl;
        if (t < TP_) pot[((size_t)b * TP_ + t) * O_ + o] = acch[tl] + accl[tl];
    }
}

// ===========================================================================
// SCAN (shared by both paths)
// ===========================================================================
__global__ void scan_prep(const float* __restrict__ pot, unsigned char* __restrict__ code) {
    int idx = blockIdx.x * 256 + threadIdx.x;
    if (idx >= B_ * TP_ * N_) return;
    int n  = idx & (N_ - 1);
    int bt = idx >> 8;
    const float* p = pot + (size_t)bt * O_ + n;
    float best = p[0]; int bo = 0;
#pragma unroll
    for (int oc = 1; oc < OC_; ++oc) {
        float v = p[oc * N_];
        if (v > best) { best = v; bo = oc; }
    }
    code[idx] = ((best + 16.0f) > 32.0f) ? (unsigned char)(bo + 1) : (unsigned char)0;
}

__global__ void scan_run(const unsigned char* __restrict__ code, float* __restrict__ out) {
    int idx = blockIdx.x * 256 + threadIdx.x;
    if (idx >= B_ * N_) return;
    int b = idx >> 8, n = idx & 255;
    const unsigned char* c = code + (size_t)b * TP_ * N_ + n;
    int t = 0;
    while (t < TP_) {
        unsigned char v = c[(size_t)t * N_];
        if (v) {
            out[(((size_t)b * OC_ + (v - 1)) * N_ + n) * TP_ + t] = 1.0f;
            t += KS_;
        } else {
            ++t;
        }
    }
}

// ===========================================================================
extern "C" void kernel_launch(void* const* d_in, const int* in_sizes, int n_in,
                              void* d_out, int out_size, void* d_ws, size_t ws_size,
                              hipStream_t stream) {
    const float* x = (const float*)d_in[0];   // [16][1][64][512] binary
    const float* w = (const float*)d_in[1];   // [2560][64]
    float* out = (float*)d_out;               // [16][10][256][561]

    char* ws = (char*)d_ws;
    const size_t szA = (size_t)MROWS * KTOT * 2;   //  55,836,672
    const size_t szB = (size_t)NCOLS * KTOT * 2;   //  31,457,280
    const size_t szP = (size_t)MVAL * O_ * 4;      //  91,914,240
    const size_t szC = (size_t)B_ * TP_ * N_;      //   2,297,856
    const size_t need = szA + szB + szP + szC;     // ~173 MB

    hipMemsetAsync(d_out, 0, (size_t)out_size * sizeof(float), stream);

    if (ws_size >= need) {
        _Float16* Aim = (_Float16*)ws;
        _Float16* Bt  = (_Float16*)(ws + szA);
        float* pot    = (float*)(ws + szA + szB);
        unsigned char* code = (unsigned char*)(ws + szA + szB + szP);

        prep_A<<<(MROWS * KTOT + 255) / 256, 256, 0, stream>>>(x, Aim);
        prep_B<<<(O_ * KTOT + 255) / 256, 256, 0, stream>>>(w, Bt);
        gemm_kernel<<<dim3(NCOLS / 128, MROWS / 128), 256, 0, stream>>>(Aim, Bt, pot);
        scan_prep<<<(B_ * TP_ * N_ + 255) / 256, 256, 0, stream>>>(pot, code);
        scan_run<<<(B_ * N_ + 255) / 256, 256, 0, stream>>>(code, out);
    } else {
        // fallback: round-1 direct conv (needs ~95 MB)
        size_t pot_bytes  = (size_t)B_ * TP_ * O_ * sizeof(float);
        size_t code_bytes = (size_t)B_ * TP_ * N_;
        float* pot = (float*)ws;
        unsigned char* code = (unsigned char*)(ws + pot_bytes);
        float* wT = (float*)(ws + pot_bytes + code_bytes);

        transpose_w<<<(O_ * S_ + 255) / 256, 256, 0, stream>>>(w, wT);
        conv_kernel<<<dim3(O_ / 256, B_, (TP_ + TT - 1) / TT), 256, 0, stream>>>(x, wT, pot);
        scan_prep<<<(B_ * TP_ * N_ + 255) / 256, 256, 0, stream>>>(pot, code);
        scan_run<<<(B_ * N_ + 255) / 256, 256, 0, stream>>>(code, out);
    }
}

// Round 3
// 461.668 us; speedup vs baseline: 6.0648x; 1.1010x over previous
//
#include <hip/hip_runtime.h>

// Problem constants (from reference)
#define B_   16
#define OC_  10
#define N_   256
#define O_   2560   // OC_*N_
#define S_   64     // synapses
#define T_   512
#define KS_  48
#define TP_  561    // T + KS + 1
#define TT   24     // (fallback conv) time steps per thread
#define WROW 72     // (fallback conv) LDS row stride

// GEMM path constants
#define KTOT  3072          // S_*KS_
#define MROWS 9088          // 71*128 (B_*TP_=8976 padded)
#define MVAL  8976
#define NB    40            // o-blocks of 64
#define BROWS (NB*192)      // 7680 Bt rows (3 digit planes of 64 per o-block)

using i32x4 = __attribute__((ext_vector_type(4))) int;

// ===========================================================================
// prep_A8: im2col of x -> A[bt][k] int8 in {0,1}, k = i*48+j, packed 4/thread
// ===========================================================================
__global__ void prep_A8(const float* __restrict__ x, unsigned char* __restrict__ A) {
    int idx = blockIdx.x * 256 + threadIdx.x;
    if (idx >= MROWS * KTOT / 4) return;
    int bt = idx / (KTOT / 4);
    int k4 = (idx - bt * (KTOT / 4)) * 4;
    int b = bt / TP_, t = bt - b * TP_;
    unsigned v = 0;
    if (bt < MVAL) {
#pragma unroll
        for (int e = 0; e < 4; ++e) {
            int k = k4 + e;
            int i = k / KS_, j = k - i * KS_;
            int ts = t - 1 - j;
            unsigned bit = 0;
            if (ts >= 0 && ts < T_) bit = (x[((b << 6) + i) * T_ + ts] != 0.0f) ? 1u : 0u;
            v |= bit << (8 * e);
        }
    }
    ((unsigned*)A)[idx] = v;
}

// ===========================================================================
// prep_B8: taps -> 22-bit fixed point -> three signed base-256 digits (i8).
// Row layout: n" = (o>>6)*192 + d*64 + (o&63)  -> all 3 digits of an output o
// fall in ONE gemm block and ONE lane.
// ===========================================================================
__global__ void prep_B8(const float* __restrict__ w, signed char* __restrict__ Bt) {
    int idx = blockIdx.x * 256 + threadIdx.x;  // o*3072 + k
    if (idx >= O_ * KTOT) return;
    int o = idx / KTOT;
    int k = idx - o * KTOT;
    int i = k / KS_, j = k - i * KS_;
    float wv = w[(o << 6) + i];
    float rise = (float)j * 0.0625f;
    float leak = -((float)j - wv * 16.0f) * 0.03125f + wv;
    float kv   = fmaxf(0.0f, fminf(rise, leak));     // in [0,1]
    int q  = (int)lrintf(kv * 4194304.0f);           // kv * 2^22
    int d0 = ((q + 128) & 255) - 128;                // [-128,127]
    int q1 = (q - d0) >> 8;
    int d1 = ((q1 + 128) & 255) - 128;               // [-128,127]
    int d2 = (q1 - d1) >> 8;                         // [0,64]
    size_t base = ((size_t)(o >> 6) * 192 + (o & 63)) * KTOT + k;
    Bt[base]                      = (signed char)d0;
    Bt[base + (size_t)64 * KTOT]  = (signed char)d1;
    Bt[base + (size_t)128 * KTOT] = (signed char)d2;
}

// ===========================================================================
// gemm_i8: block = 128 bt x (64 o x 3 digits), BK=64, global_load_lds staging,
// mfma_i32_16x16x64_i8.  int32 accumulation is EXACT (|sum| <= 3072*128).
// Epilogue combines the 3 digit accumulators in-lane in double.
// ===========================================================================
__global__ __launch_bounds__(256) void gemm_i8(
    const unsigned char* __restrict__ A,  // [MROWS][KTOT] in {0,1}
    const signed char*  __restrict__ Bt,  // [BROWS][KTOT]
    float* __restrict__ pot)              // [MVAL][O_]
{
    __shared__ __align__(16) signed char Ash[128][64];
    __shared__ __align__(16) signed char Bsh[192][64];

    const int tid  = threadIdx.x;
    const int lane = tid & 63;
    const int wave = tid >> 6;
    const int row0  = blockIdx.y * 128;    // bt base
    const int ob    = blockIdx.x;          // o-block (64 outputs)
    const int bcol0 = ob * 192;            // Bt row base
    const int m_base = (wave & 1) * 64;
    const int o_base = (wave >> 1) * 32;
    const int lrow = lane & 15;
    const int quad = lane >> 4;

    i32x4 acc[4][6];                       // [m-tile][d*2+q]
#pragma unroll
    for (int mi = 0; mi < 4; ++mi)
#pragma unroll
        for (int f = 0; f < 6; ++f)
            acc[mi][f] = (i32x4){0, 0, 0, 0};

    signed char* AshP = &Ash[0][0];
    signed char* BshP = &Bsh[0][0];

    for (int kb = 0; kb < KTOT; kb += 64) {
#pragma unroll
        for (int s = 0; s < 2; ++s) {      // A: 128 rows x 64B = 512 chunks
            int seg = tid + 256 * s;
            int r = seg >> 2, p = seg & 3;
            __builtin_amdgcn_global_load_lds(
                (const __attribute__((address_space(1))) void*)
                    (A + (size_t)(row0 + r) * KTOT + kb + p * 16),
                (__attribute__((address_space(3))) void*)(AshP + seg * 16),
                16, 0, 0);
        }
#pragma unroll
        for (int s = 0; s < 3; ++s) {      // B: 192 rows x 64B = 768 chunks
            int seg = tid + 256 * s;
            int r = seg >> 2, p = seg & 3;
            __builtin_amdgcn_global_load_lds(
                (const __attribute__((address_space(1))) void*)
                    (Bt + (size_t)(bcol0 + r) * KTOT + kb + p * 16),
                (__attribute__((address_space(3))) void*)(BshP + seg * 16),
                16, 0, 0);
        }
        __syncthreads();

        i32x4 af[4], bf[6];
#pragma unroll
        for (int mi = 0; mi < 4; ++mi)
            af[mi] = *(const i32x4*)&Ash[m_base + mi * 16 + lrow][quad * 16];
#pragma unroll
        for (int d = 0; d < 3; ++d)
#pragma unroll
            for (int q = 0; q < 2; ++q)
                bf[d * 2 + q] = *(const i32x4*)
                    &Bsh[d * 64 + o_base + q * 16 + lrow][quad * 16];

#pragma unroll
        for (int mi = 0; mi < 4; ++mi)
#pragma unroll
            for (int f = 0; f < 6; ++f)
                acc[mi][f] = __builtin_amdgcn_mfma_i32_16x16x64_i8(
                    af[mi], bf[f], acc[mi][f], 0, 0, 0);
        __syncthreads();
    }

    // epilogue: C/D layout col=lane&15, row=quad*4+reg (dtype-independent).
#pragma unroll
    for (int mi = 0; mi < 4; ++mi) {
#pragma unroll
        for (int q = 0; q < 2; ++q) {
#pragma unroll
            for (int r = 0; r < 4; ++r) {
                int bt = row0 + m_base + mi * 16 + quad * 4 + r;
                int o  = ob * 64 + o_base + q * 16 + lrow;
                double pq = ((double)acc[mi][q][r]
                           + 256.0   * (double)acc[mi][2 + q][r]
                           + 65536.0 * (double)acc[mi][4 + q][r])
                          * (1.0 / 4194304.0);
                if (bt < MVAL) pot[(size_t)bt * O_ + o] = (float)pq;
            }
        }
    }
}

// ===========================================================================
// FALLBACK (round-1 direct conv) — only if ws_size too small
// ===========================================================================
__global__ void transpose_w(const float* __restrict__ w, float* __restrict__ wT) {
    int idx = blockIdx.x * 256 + threadIdx.x;
    if (idx >= O_ * S_) return;
    int o = idx >> 6, i = idx & 63;
    wT[i * O_ + o] = w[idx];
}

__global__ __launch_bounds__(256) void conv_kernel(
    const float* __restrict__ x, const float* __restrict__ wT,
    float* __restrict__ pot)
{
    const int b  = blockIdx.y;
    const int t0 = blockIdx.z * TT;
    const int o  = blockIdx.x * 256 + threadIdx.x;

    __shared__ __align__(16) float xsh[S_][WROW];
    for (int idx = threadIdx.x; idx < S_ * WROW; idx += 256) {
        int i = idx / WROW, m = idx - i * WROW;
        int t = t0 - KS_ + m;
        float v = 0.0f;
        if (t >= 0 && t < T_) v = x[(b * S_ + i) * T_ + t];
        xsh[i][m] = v;
    }
    __syncthreads();

    float acch[TT], accl[TT];
#pragma unroll
    for (int tl = 0; tl < TT; ++tl) { acch[tl] = 0.0f; accl[tl] = 0.0f; }

    for (int i = 0; i < S_; ++i) {
        float xw[WROW];
#pragma unroll
        for (int w4 = 0; w4 < WROW / 4; ++w4) {
            const float4 v = *reinterpret_cast<const float4*>(&xsh[i][w4 * 4]);
            xw[w4 * 4 + 0] = v.x; xw[w4 * 4 + 1] = v.y;
            xw[w4 * 4 + 2] = v.z; xw[w4 * 4 + 3] = v.w;
        }
        const float wv = wT[i * O_ + o];
#pragma unroll
        for (int j = 1; j < KS_; ++j) {
            float rise = (float)j * 0.0625f;
            float leak = -((float)j - wv * 16.0f) * 0.03125f + wv;
            float kv   = fmaxf(0.0f, fminf(rise, leak));
            float khi  = rintf(kv * 4096.0f) * 2.44140625e-4f;
            float klo  = kv - khi;
#pragma unroll
            for (int tl = 0; tl < TT; ++tl) {
                float xv = xw[tl + (KS_ - 1) - j];
                acch[tl] = fmaf(xv, khi, acch[tl]);
                accl[tl] = fmaf(xv, klo, accl[tl]);
            }
        }
    }
#pragma unroll
    for (int tl = 0; tl < TT; ++tl) {
        int t = t0 + tl;
        if (t < TP_) pot[((size_t)b * TP_ + t) * O_ + o] = acch[tl] + accl[tl];
    }
}

// ===========================================================================
// SCAN
// ===========================================================================
__global__ void scan_prep(const float* __restrict__ pot, unsigned char* __restrict__ code) {
    int idx = blockIdx.x * 256 + threadIdx.x;
    if (idx >= B_ * TP_ * N_) return;
    int n  = idx & (N_ - 1);
    int bt = idx >> 8;
    const float* p = pot + (size_t)bt * O_ + n;
    float best = p[0]; int bo = 0;
#pragma unroll
    for (int oc = 1; oc < OC_; ++oc) {
        float v = p[oc * N_];
        if (v > best) { best = v; bo = oc; } // strict > keeps FIRST max (argmax)
    }
    code[idx] = ((best + 16.0f) > 32.0f) ? (unsigned char)(bo + 1) : (unsigned char)0;
}

// Batched walk: each outer iteration loads 48 INDEPENDENT bytes (one vmcnt
// batch, ~1 mem latency), then walks in registers. Every iteration advances
// >= 48 (spike jump = k+48, no-spike = 48) -> <= 12 latency exposures
// instead of ~561 dependent ones.
__global__ void scan_run(const unsigned char* __restrict__ code, float* __restrict__ out) {
    int idx = blockIdx.x * 256 + threadIdx.x;
    if (idx >= B_ * N_) return;
    int b = idx >> 8, n = idx & 255;
    const unsigned char* c = code + (size_t)b * TP_ * N_ + n;
    int t = 0;
    while (t < TP_) {
        unsigned char buf[KS_];
#pragma unroll
        for (int k = 0; k < KS_; ++k) {
            int tt = t + k;
            buf[k] = (tt < TP_) ? c[(size_t)tt * N_] : (unsigned char)0;
        }
        int adv = KS_;
#pragma unroll
        for (int k = 0; k < KS_; ++k) {
            if (buf[k]) {
                out[(((size_t)b * OC_ + (buf[k] - 1)) * N_ + n) * TP_ + (t + k)] = 1.0f;
                adv = k + KS_;
                break;
            }
        }
        t += adv;
    }
}

// ===========================================================================
extern "C" void kernel_launch(void* const* d_in, const int* in_sizes, int n_in,
                              void* d_out, int out_size, void* d_ws, size_t ws_size,
                              hipStream_t stream) {
    const float* x = (const float*)d_in[0];   // [16][1][64][512] binary
    const float* w = (const float*)d_in[1];   // [2560][64]
    float* out = (float*)d_out;               // [16][10][256][561]

    char* ws = (char*)d_ws;
    const size_t szA = (size_t)MROWS * KTOT;       //  27,918,336
    const size_t szB = (size_t)BROWS * KTOT;       //  23,592,960
    const size_t szP = (size_t)MVAL * O_ * 4;      //  91,914,240
    const size_t szC = (size_t)B_ * TP_ * N_;      //   2,297,856
    const size_t need = szA + szB + szP + szC;     // ~145.7 MB

    hipMemsetAsync(d_out, 0, (size_t)out_size * sizeof(float), stream);

    if (ws_size >= need) {
        unsigned char* Aim = (unsigned char*)ws;
        signed char* Bt    = (signed char*)(ws + szA);
        float* pot         = (float*)(ws + szA + szB);
        unsigned char* code = (unsigned char*)(ws + szA + szB + szP);

        prep_A8<<<(MROWS * KTOT / 4 + 255) / 256, 256, 0, stream>>>(x, Aim);
        prep_B8<<<(O_ * KTOT + 255) / 256, 256, 0, stream>>>(w, Bt);
        gemm_i8<<<dim3(NB, MROWS / 128), 256, 0, stream>>>(Aim, Bt, pot);
        scan_prep<<<(B_ * TP_ * N_ + 255) / 256, 256, 0, stream>>>(pot, code);
        scan_run<<<(B_ * N_ + 255) / 256, 256, 0, stream>>>(code, out);
    } else {
        // fallback: round-1 direct conv (needs ~95 MB)
        size_t pot_bytes  = (size_t)B_ * TP_ * O_ * sizeof(float);
        size_t code_bytes = (size_t)B_ * TP_ * N_;
        float* pot = (float*)ws;
        unsigned char* code = (unsigned char*)(ws + pot_bytes);
        float* wT = (float*)(ws + pot_bytes + code_bytes);

        transpose_w<<<(O_ * S_ + 255) / 256, 256, 0, stream>>>(w, wT);
        conv_kernel<<<dim3(O_ / 256, B_, (TP_ + TT - 1) / TT), 256, 0, stream>>>(x, wT, pot);
        scan_prep<<<(B_ * TP_ * N_ + 255) / 256, 256, 0, stream>>>(pot, code);
        scan_run<<<(B_ * N_ + 255) / 256, 256, 0, stream>>>(code, out);
    }
}

// Round 4
// 401.362 us; speedup vs baseline: 6.9761x; 1.1503x over previous
//
#include <hip/hip_runtime.h>

// Problem constants (from reference)
#define B_   16
#define OC_  10
#define N_   256
#define O_   2560   // OC_*N_
#define S_   64     // synapses
#define T_   512
#define KS_  48
#define TP_  561    // T + KS + 1
#define TT   24     // (fallback conv) time steps per thread
#define WROW 72     // (fallback conv) LDS row stride

// GEMM path constants
#define KTOT  3072          // S_*KS_
#define MPAD  9024          // 47*192 (B_*TP_=8976 padded to 192-multiple)
#define MVAL  8976
#define NB    40            // o-blocks of 64
#define BROWS (NB*192)      // 7680 Bt rows: (o>>5)*96 + d*32 + (o&31)

using i32x4 = __attribute__((ext_vector_type(4))) int;

// ===========================================================================
// prep_A8: im2col of x -> A[bt][k] int8 in {0,1}, k = i*48+j, packed 4/thread
// ===========================================================================
__global__ void prep_A8(const float* __restrict__ x, unsigned char* __restrict__ A) {
    int idx = blockIdx.x * 256 + threadIdx.x;
    if (idx >= MPAD * KTOT / 4) return;
    int bt = idx / (KTOT / 4);
    int k4 = (idx - bt * (KTOT / 4)) * 4;
    int b = bt / TP_, t = bt - b * TP_;
    unsigned v = 0;
    if (bt < MVAL) {
#pragma unroll
        for (int e = 0; e < 4; ++e) {
            int k = k4 + e;
            int i = k / KS_, j = k - i * KS_;
            int ts = t - 1 - j;
            unsigned bit = 0;
            if (ts >= 0 && ts < T_) bit = (x[((b << 6) + i) * T_ + ts] != 0.0f) ? 1u : 0u;
            v |= bit << (8 * e);
        }
    }
    ((unsigned*)A)[idx] = v;
}

// ===========================================================================
// prep_B8: taps -> 22-bit fixed point -> three signed base-256 digits (i8).
// Row layout: n" = (o>>5)*96 + d*32 + (o&31)  -> each 96-row group holds the
// complete digit triples of 32 outputs (in-lane epilogue combine).
// ===========================================================================
__global__ void prep_B8(const float* __restrict__ w, signed char* __restrict__ Bt) {
    int idx = blockIdx.x * 256 + threadIdx.x;  // o*3072 + k
    if (idx >= O_ * KTOT) return;
    int o = idx / KTOT;
    int k = idx - o * KTOT;
    int i = k / KS_, j = k - i * KS_;
    float wv = w[(o << 6) + i];
    float rise = (float)j * 0.0625f;
    float leak = -((float)j - wv * 16.0f) * 0.03125f + wv;
    float kv   = fmaxf(0.0f, fminf(rise, leak));     // in [0,1]
    int q  = (int)lrintf(kv * 4194304.0f);           // kv * 2^22
    int d0 = ((q + 128) & 255) - 128;                // [-128,127]
    int q1 = (q - d0) >> 8;
    int d1 = ((q1 + 128) & 255) - 128;               // [-128,127]
    int d2 = (q1 - d1) >> 8;                         // [0,64]
    size_t base = ((size_t)(o >> 5) * 96 + (o & 31)) * KTOT + k;
    Bt[base]                      = (signed char)d0;
    Bt[base + (size_t)32 * KTOT]  = (signed char)d1;
    Bt[base + (size_t)64 * KTOT]  = (signed char)d2;
}

// ===========================================================================
// gemm_i8: block = 192 bt x 192 n-rows (64 o x 3 digits), 4 waves of 96x96.
// LDS-read-BW-bound -> maximize register reuse: 6x6 frags = 36 MFMA per
// 12 ds_read_b128.  mfma_i32_16x16x64_i8, exact int32 accumulation.
// ===========================================================================
__global__ __launch_bounds__(256, 2) void gemm_i8(
    const unsigned char* __restrict__ A,  // [MPAD][KTOT] in {0,1}
    const signed char*  __restrict__ Bt,  // [BROWS][KTOT]
    float* __restrict__ pot)              // [MVAL][O_]
{
    __shared__ __align__(16) signed char Ash[192][64];
    __shared__ __align__(16) signed char Bsh[192][64];

    const int tid  = threadIdx.x;
    const int lane = tid & 63;
    const int wave = tid >> 6;
    const int row0  = blockIdx.y * 192;    // bt base
    const int ob    = blockIdx.x;          // o-block (64 outputs)
    const int bcol0 = ob * 192;            // Bt row base
    const int mh = (wave & 1) * 96;        // wave m-half
    const int gh = (wave >> 1) * 96;       // wave o-group half (32 outputs)
    const int lrow = lane & 15;
    const int quad = lane >> 4;

    i32x4 acc[6][6];                       // [mi][f], f = 2*d + q
#pragma unroll
    for (int mi = 0; mi < 6; ++mi)
#pragma unroll
        for (int f = 0; f < 6; ++f)
            acc[mi][f] = (i32x4){0, 0, 0, 0};

    signed char* AshP = &Ash[0][0];
    signed char* BshP = &Bsh[0][0];

    for (int kb = 0; kb < KTOT; kb += 64) {
#pragma unroll
        for (int s = 0; s < 3; ++s) {      // A: 192 rows x 64B = 768 chunks
            int seg = tid + 256 * s;
            int r = seg >> 2, p = seg & 3;
            __builtin_amdgcn_global_load_lds(
                (const __attribute__((address_space(1))) void*)
                    (A + (size_t)(row0 + r) * KTOT + kb + p * 16),
                (__attribute__((address_space(3))) void*)(AshP + seg * 16),
                16, 0, 0);
        }
#pragma unroll
        for (int s = 0; s < 3; ++s) {      // B: 192 rows x 64B = 768 chunks
            int seg = tid + 256 * s;
            int r = seg >> 2, p = seg & 3;
            __builtin_amdgcn_global_load_lds(
                (const __attribute__((address_space(1))) void*)
                    (Bt + (size_t)(bcol0 + r) * KTOT + kb + p * 16),
                (__attribute__((address_space(3))) void*)(BshP + seg * 16),
                16, 0, 0);
        }
        __syncthreads();

        i32x4 af[6], bf[6];
#pragma unroll
        for (int mi = 0; mi < 6; ++mi)
            af[mi] = *(const i32x4*)&Ash[mh + mi * 16 + lrow][quad * 16];
#pragma unroll
        for (int f = 0; f < 6; ++f)
            bf[f] = *(const i32x4*)&Bsh[gh + f * 16 + lrow][quad * 16];

#pragma unroll
        for (int mi = 0; mi < 6; ++mi)
#pragma unroll
            for (int f = 0; f < 6; ++f)
                acc[mi][f] = __builtin_amdgcn_mfma_i32_16x16x64_i8(
                    af[mi], bf[f], acc[mi][f], 0, 0, 0);
        __syncthreads();
    }

    // epilogue: C/D layout col=lane&15 (n), row=quad*4+reg (m).
#pragma unroll
    for (int mi = 0; mi < 6; ++mi) {
#pragma unroll
        for (int q = 0; q < 2; ++q) {
#pragma unroll
            for (int r = 0; r < 4; ++r) {
                int bt = row0 + mh + mi * 16 + quad * 4 + r;
                int o  = ob * 64 + (wave >> 1) * 32 + q * 16 + lrow;
                double pq = ((double)acc[mi][q][r]
                           + 256.0   * (double)acc[mi][2 + q][r]
                           + 65536.0 * (double)acc[mi][4 + q][r])
                          * (1.0 / 4194304.0);
                if (bt < MVAL) pot[(size_t)bt * O_ + o] = (float)pq;
            }
        }
    }
}

// ===========================================================================
// FALLBACK (round-1 direct conv) — only if ws_size too small
// ===========================================================================
__global__ void transpose_w(const float* __restrict__ w, float* __restrict__ wT) {
    int idx = blockIdx.x * 256 + threadIdx.x;
    if (idx >= O_ * S_) return;
    int o = idx >> 6, i = idx & 63;
    wT[i * O_ + o] = w[idx];
}

__global__ __launch_bounds__(256) void conv_kernel(
    const float* __restrict__ x, const float* __restrict__ wT,
    float* __restrict__ pot)
{
    const int b  = blockIdx.y;
    const int t0 = blockIdx.z * TT;
    const int o  = blockIdx.x * 256 + threadIdx.x;

    __shared__ __align__(16) float xsh[S_][WROW];
    for (int idx = threadIdx.x; idx < S_ * WROW; idx += 256) {
        int i = idx / WROW, m = idx - i * WROW;
        int t = t0 - KS_ + m;
        float v = 0.0f;
        if (t >= 0 && t < T_) v = x[(b * S_ + i) * T_ + t];
        xsh[i][m] = v;
    }
    __syncthreads();

    float acch[TT], accl[TT];
#pragma unroll
    for (int tl = 0; tl < TT; ++tl) { acch[tl] = 0.0f; accl[tl] = 0.0f; }

    for (int i = 0; i < S_; ++i) {
        float xw[WROW];
#pragma unroll
        for (int w4 = 0; w4 < WROW / 4; ++w4) {
            const float4 v = *reinterpret_cast<const float4*>(&xsh[i][w4 * 4]);
            xw[w4 * 4 + 0] = v.x; xw[w4 * 4 + 1] = v.y;
            xw[w4 * 4 + 2] = v.z; xw[w4 * 4 + 3] = v.w;
        }
        const float wv = wT[i * O_ + o];
#pragma unroll
        for (int j = 1; j < KS_; ++j) {
            float rise = (float)j * 0.0625f;
            float leak = -((float)j - wv * 16.0f) * 0.03125f + wv;
            float kv   = fmaxf(0.0f, fminf(rise, leak));
            float khi  = rintf(kv * 4096.0f) * 2.44140625e-4f;
            float klo  = kv - khi;
#pragma unroll
            for (int tl = 0; tl < TT; ++tl) {
                float xv = xw[tl + (KS_ - 1) - j];
                acch[tl] = fmaf(xv, khi, acch[tl]);
                accl[tl] = fmaf(xv, klo, accl[tl]);
            }
        }
    }
#pragma unroll
    for (int tl = 0; tl < TT; ++tl) {
        int t = t0 + tl;
        if (t < TP_) pot[((size_t)b * TP_ + t) * O_ + o] = acch[tl] + accl[tl];
    }
}

// ===========================================================================
// SCAN
// ===========================================================================
__global__ void scan_prep(const float* __restrict__ pot, unsigned char* __restrict__ code) {
    int idx = blockIdx.x * 256 + threadIdx.x;
    if (idx >= B_ * TP_ * N_) return;
    int n  = idx & (N_ - 1);
    int bt = idx >> 8;
    const float* p = pot + (size_t)bt * O_ + n;
    float best = p[0]; int bo = 0;
#pragma unroll
    for (int oc = 1; oc < OC_; ++oc) {
        float v = p[oc * N_];
        if (v > best) { best = v; bo = oc; } // strict > keeps FIRST max (argmax)
    }
    code[idx] = ((best + 16.0f) > 32.0f) ? (unsigned char)(bo + 1) : (unsigned char)0;
}

// Batched walk: each outer iteration loads 48 INDEPENDENT bytes (one vmcnt
// batch), then walks in registers; every iteration advances >= 48.
__global__ void scan_run(const unsigned char* __restrict__ code, float* __restrict__ out) {
    int idx = blockIdx.x * 256 + threadIdx.x;
    if (idx >= B_ * N_) return;
    int b = idx >> 8, n = idx & 255;
    const unsigned char* c = code + (size_t)b * TP_ * N_ + n;
    int t = 0;
    while (t < TP_) {
        unsigned char buf[KS_];
#pragma unroll
        for (int k = 0; k < KS_; ++k) {
            int tt = t + k;
            buf[k] = (tt < TP_) ? c[(size_t)tt * N_] : (unsigned char)0;
        }
        int adv = KS_;
#pragma unroll
        for (int k = 0; k < KS_; ++k) {
            if (buf[k]) {
                out[(((size_t)b * OC_ + (buf[k] - 1)) * N_ + n) * TP_ + (t + k)] = 1.0f;
                adv = k + KS_;
                break;
            }
        }
        t += adv;
    }
}

// ===========================================================================
extern "C" void kernel_launch(void* const* d_in, const int* in_sizes, int n_in,
                              void* d_out, int out_size, void* d_ws, size_t ws_size,
                              hipStream_t stream) {
    const float* x = (const float*)d_in[0];   // [16][1][64][512] binary
    const float* w = (const float*)d_in[1];   // [2560][64]
    float* out = (float*)d_out;               // [16][10][256][561]

    char* ws = (char*)d_ws;
    const size_t szA = (size_t)MPAD * KTOT;        //  27,721,728
    const size_t szB = (size_t)BROWS * KTOT;       //  23,592,960
    const size_t szP = (size_t)MVAL * O_ * 4;      //  91,914,240
    const size_t szC = (size_t)B_ * TP_ * N_;      //   2,297,856
    const size_t need = szA + szB + szP + szC;     // ~145.5 MB

    hipMemsetAsync(d_out, 0, (size_t)out_size * sizeof(float), stream);

    if (ws_size >= need) {
        unsigned char* Aim = (unsigned char*)ws;
        signed char* Bt    = (signed char*)(ws + szA);
        float* pot         = (float*)(ws + szA + szB);
        unsigned char* code = (unsigned char*)(ws + szA + szB + szP);

        prep_A8<<<(MPAD * KTOT / 4 + 255) / 256, 256, 0, stream>>>(x, Aim);
        prep_B8<<<(O_ * KTOT + 255) / 256, 256, 0, stream>>>(w, Bt);
        gemm_i8<<<dim3(NB, MPAD / 192), 256, 0, stream>>>(Aim, Bt, pot);
        scan_prep<<<(B_ * TP_ * N_ + 255) / 256, 256, 0, stream>>>(pot, code);
        scan_run<<<(B_ * N_ + 255) / 256, 256, 0, stream>>>(code, out);
    } else {
        // fallback: round-1 direct conv (needs ~95 MB)
        size_t pot_bytes  = (size_t)B_ * TP_ * O_ * sizeof(float);
        size_t code_bytes = (size_t)B_ * TP_ * N_;
        float* pot = (float*)ws;
        unsigned char* code = (unsigned char*)(ws + pot_bytes);
        float* wT = (float*)(ws + pot_bytes + code_bytes);

        transpose_w<<<(O_ * S_ + 255) / 256, 256, 0, stream>>>(w, wT);
        conv_kernel<<<dim3(O_ / 256, B_, (TP_ + TT - 1) / TT), 256, 0, stream>>>(x, wT, pot);
        scan_prep<<<(B_ * TP_ * N_ + 255) / 256, 256, 0, stream>>>(pot, code);
        scan_run<<<(B_ * N_ + 255) / 256, 256, 0, stream>>>(code, out);
    }
}

// Round 5
// 397.489 us; speedup vs baseline: 7.0440x; 1.0097x over previous
//
#include <hip/hip_runtime.h>

// Problem constants (from reference)
#define B_   16
#define OC_  10
#define N_   256
#define O_   2560   // OC_*N_
#define S_   64     // synapses
#define T_   512
#define KS_  48
#define TP_  561    // T + KS + 1
#define TT   24     // (fallback conv) time steps per thread
#define WROW 72     // (fallback conv) LDS row stride

// GEMM path constants
#define KTOT  3072          // S_*KS_
#define MPAD  9024          // 47*192 (B_*TP_=8976 padded to 192-multiple)
#define MVAL  8976
#define NB    40            // o-blocks of 64
#define BROWS (NB*192)      // 7680 Bt rows: (o>>5)*96 + d*32 + (o&31)

using i32x4 = __attribute__((ext_vector_type(4))) int;

// ===========================================================================
// prep_A8: im2col of x -> A[bt][k] int8 in {0,1}, k = i*48+j, packed 4/thread.
// Chunk-swizzled storage: within each 64-B K-block, 16-B chunk p is stored at
// position p ^ ((bt>>1)&3).  Makes the gemm's ds_read_b128 bank-conflict-free
// (tile bases are multiples of 8 rows, so the key is (lrow>>1)&3 at read).
// ===========================================================================
__global__ void prep_A8(const float* __restrict__ x, unsigned char* __restrict__ A) {
    int idx = blockIdx.x * 256 + threadIdx.x;
    if (idx >= MPAD * KTOT / 4) return;
    int bt = idx / (KTOT / 4);
    int k4 = (idx - bt * (KTOT / 4)) * 4;
    int b = bt / TP_, t = bt - b * TP_;
    unsigned v = 0;
    if (bt < MVAL) {
#pragma unroll
        for (int e = 0; e < 4; ++e) {
            int k = k4 + e;
            int i = k / KS_, j = k - i * KS_;
            int ts = t - 1 - j;
            unsigned bit = 0;
            if (ts >= 0 && ts < T_) bit = (x[((b << 6) + i) * T_ + ts] != 0.0f) ? 1u : 0u;
            v |= bit << (8 * e);
        }
    }
    int s = (bt >> 1) & 3;
    int p = (k4 >> 4) & 3;
    size_t baddr = (size_t)bt * KTOT + (k4 & ~63) + ((p ^ s) << 4) + (k4 & 15);
    *(unsigned*)(A + baddr) = v;
}

// ===========================================================================
// prep_B8: taps -> 22-bit fixed point -> three signed base-256 digits (i8).
// Row layout: n" = (o>>5)*96 + d*32 + (o&31); same chunk swizzle, key
// ((o&31)>>1)&3 (identical for all 3 digit rows since 32|d-offset).
// ===========================================================================
__global__ void prep_B8(const float* __restrict__ w, signed char* __restrict__ Bt) {
    int idx = blockIdx.x * 256 + threadIdx.x;  // o*3072 + k
    if (idx >= O_ * KTOT) return;
    int o = idx / KTOT;
    int k = idx - o * KTOT;
    int i = k / KS_, j = k - i * KS_;
    float wv = w[(o << 6) + i];
    float rise = (float)j * 0.0625f;
    float leak = -((float)j - wv * 16.0f) * 0.03125f + wv;
    float kv   = fmaxf(0.0f, fminf(rise, leak));     // in [0,1]
    int q  = (int)lrintf(kv * 4194304.0f);           // kv * 2^22
    int d0 = ((q + 128) & 255) - 128;                // [-128,127]
    int q1 = (q - d0) >> 8;
    int d1 = ((q1 + 128) & 255) - 128;               // [-128,127]
    int d2 = (q1 - d1) >> 8;                         // [0,64]
    int s   = (o >> 1) & 3;                          // == ((o&31)>>1)&3
    int ksw = (k & ~63) | ((((k >> 4) & 3) ^ s) << 4) | (k & 15);
    size_t base = ((size_t)(o >> 5) * 96 + (o & 31)) * KTOT + ksw;
    Bt[base]                      = (signed char)d0;
    Bt[base + (size_t)32 * KTOT]  = (signed char)d1;
    Bt[base + (size_t)64 * KTOT]  = (signed char)d2;
}

// ===========================================================================
// gemm_i8: block = 192 bt x 192 n-rows (64 o x 3 digits), 4 waves of 96x96.
// 6x6 frags = 36 MFMA per 12 ds_read_b128; chunk-swizzled LDS reads
// (quad ^ (lrow>>1)&3) -> conflict-free b128 phases.  Exact int32 acc.
// ===========================================================================
__global__ __launch_bounds__(256, 2) void gemm_i8(
    const unsigned char* __restrict__ A,  // [MPAD][KTOT] in {0,1}, swizzled
    const signed char*  __restrict__ Bt,  // [BROWS][KTOT], swizzled
    float* __restrict__ pot)              // [MVAL][O_]
{
    __shared__ __align__(16) signed char Ash[192][64];
    __shared__ __align__(16) signed char Bsh[192][64];

    const int tid  = threadIdx.x;
    const int lane = tid & 63;
    const int wave = tid >> 6;
    const int row0  = blockIdx.y * 192;    // bt base (multiple of 192 -> mod 8 == 0)
    const int ob    = blockIdx.x;          // o-block (64 outputs)
    const int bcol0 = ob * 192;            // Bt row base
    const int mh = (wave & 1) * 96;        // wave m-half
    const int gh = (wave >> 1) * 96;       // wave o-group half (32 outputs)
    const int lrow = lane & 15;
    const int quad = lane >> 4;
    const int coff = ((quad ^ ((lrow >> 1) & 3)) << 4);  // swizzled chunk column

    i32x4 acc[6][6];                       // [mi][f], f = 2*d + q
#pragma unroll
    for (int mi = 0; mi < 6; ++mi)
#pragma unroll
        for (int f = 0; f < 6; ++f)
            acc[mi][f] = (i32x4){0, 0, 0, 0};

    signed char* AshP = &Ash[0][0];
    signed char* BshP = &Bsh[0][0];

    for (int kb = 0; kb < KTOT; kb += 64) {
#pragma unroll
        for (int s = 0; s < 3; ++s) {      // A: 192 rows x 64B = 768 chunks
            int seg = tid + 256 * s;
            int r = seg >> 2, p = seg & 3;
            __builtin_amdgcn_global_load_lds(
                (const __attribute__((address_space(1))) void*)
                    (A + (size_t)(row0 + r) * KTOT + kb + p * 16),
                (__attribute__((address_space(3))) void*)(AshP + seg * 16),
                16, 0, 0);
        }
#pragma unroll
        for (int s = 0; s < 3; ++s) {      // B: 192 rows x 64B = 768 chunks
            int seg = tid + 256 * s;
            int r = seg >> 2, p = seg & 3;
            __builtin_amdgcn_global_load_lds(
                (const __attribute__((address_space(1))) void*)
                    (Bt + (size_t)(bcol0 + r) * KTOT + kb + p * 16),
                (__attribute__((address_space(3))) void*)(BshP + seg * 16),
                16, 0, 0);
        }
        __syncthreads();

        i32x4 af[6], bf[6];
#pragma unroll
        for (int mi = 0; mi < 6; ++mi)
            af[mi] = *(const i32x4*)&Ash[mh + mi * 16 + lrow][coff];
#pragma unroll
        for (int f = 0; f < 6; ++f)
            bf[f] = *(const i32x4*)&Bsh[gh + f * 16 + lrow][coff];

#pragma unroll
        for (int mi = 0; mi < 6; ++mi)
#pragma unroll
            for (int f = 0; f < 6; ++f)
                acc[mi][f] = __builtin_amdgcn_mfma_i32_16x16x64_i8(
                    af[mi], bf[f], acc[mi][f], 0, 0, 0);
        __syncthreads();
    }

    // epilogue: C/D layout col=lane&15 (n), row=quad*4+reg (m).
#pragma unroll
    for (int mi = 0; mi < 6; ++mi) {
#pragma unroll
        for (int q = 0; q < 2; ++q) {
#pragma unroll
            for (int r = 0; r < 4; ++r) {
                int bt = row0 + mh + mi * 16 + quad * 4 + r;
                int o  = ob * 64 + (wave >> 1) * 32 + q * 16 + lrow;
                double pq = ((double)acc[mi][q][r]
                           + 256.0   * (double)acc[mi][2 + q][r]
                           + 65536.0 * (double)acc[mi][4 + q][r])
                          * (1.0 / 4194304.0);
                if (bt < MVAL) pot[(size_t)bt * O_ + o] = (float)pq;
            }
        }
    }
}

// ===========================================================================
// FALLBACK (round-1 direct conv) — only if ws_size too small
// ===========================================================================
__global__ void transpose_w(const float* __restrict__ w, float* __restrict__ wT) {
    int idx = blockIdx.x * 256 + threadIdx.x;
    if (idx >= O_ * S_) return;
    int o = idx >> 6, i = idx & 63;
    wT[i * O_ + o] = w[idx];
}

__global__ __launch_bounds__(256) void conv_kernel(
    const float* __restrict__ x, const float* __restrict__ wT,
    float* __restrict__ pot)
{
    const int b  = blockIdx.y;
    const int t0 = blockIdx.z * TT;
    const int o  = blockIdx.x * 256 + threadIdx.x;

    __shared__ __align__(16) float xsh[S_][WROW];
    for (int idx = threadIdx.x; idx < S_ * WROW; idx += 256) {
        int i = idx / WROW, m = idx - i * WROW;
        int t = t0 - KS_ + m;
        float v = 0.0f;
        if (t >= 0 && t < T_) v = x[(b * S_ + i) * T_ + t];
        xsh[i][m] = v;
    }
    __syncthreads();

    float acch[TT], accl[TT];
#pragma unroll
    for (int tl = 0; tl < TT; ++tl) { acch[tl] = 0.0f; accl[tl] = 0.0f; }

    for (int i = 0; i < S_; ++i) {
        float xw[WROW];
#pragma unroll
        for (int w4 = 0; w4 < WROW / 4; ++w4) {
            const float4 v = *reinterpret_cast<const float4*>(&xsh[i][w4 * 4]);
            xw[w4 * 4 + 0] = v.x; xw[w4 * 4 + 1] = v.y;
            xw[w4 * 4 + 2] = v.z; xw[w4 * 4 + 3] = v.w;
        }
        const float wv = wT[i * O_ + o];
#pragma unroll
        for (int j = 1; j < KS_; ++j) {
            float rise = (float)j * 0.0625f;
            float leak = -((float)j - wv * 16.0f) * 0.03125f + wv;
            float kv   = fmaxf(0.0f, fminf(rise, leak));
            float khi  = rintf(kv * 4096.0f) * 2.44140625e-4f;
            float klo  = kv - khi;
#pragma unroll
            for (int tl = 0; tl < TT; ++tl) {
                float xv = xw[tl + (KS_ - 1) - j];
                acch[tl] = fmaf(xv, khi, acch[tl]);
                accl[tl] = fmaf(xv, klo, accl[tl]);
            }
        }
    }
#pragma unroll
    for (int tl = 0; tl < TT; ++tl) {
        int t = t0 + tl;
        if (t < TP_) pot[((size_t)b * TP_ + t) * O_ + o] = acch[tl] + accl[tl];
    }
}

// ===========================================================================
// SCAN
// ===========================================================================
__global__ void scan_prep(const float* __restrict__ pot, unsigned char* __restrict__ code) {
    int idx = blockIdx.x * 256 + threadIdx.x;
    if (idx >= B_ * TP_ * N_) return;
    int n  = idx & (N_ - 1);
    int bt = idx >> 8;
    const float* p = pot + (size_t)bt * O_ + n;
    float best = p[0]; int bo = 0;
#pragma unroll
    for (int oc = 1; oc < OC_; ++oc) {
        float v = p[oc * N_];
        if (v > best) { best = v; bo = oc; } // strict > keeps FIRST max (argmax)
    }
    code[idx] = ((best + 16.0f) > 32.0f) ? (unsigned char)(bo + 1) : (unsigned char)0;
}

// Batched walk: each outer iteration loads 48 INDEPENDENT bytes (one vmcnt
// batch), then walks in registers; every iteration advances >= 48.
__global__ void scan_run(const unsigned char* __restrict__ code, float* __restrict__ out) {
    int idx = blockIdx.x * 256 + threadIdx.x;
    if (idx >= B_ * N_) return;
    int b = idx >> 8, n = idx & 255;
    const unsigned char* c = code + (size_t)b * TP_ * N_ + n;
    int t = 0;
    while (t < TP_) {
        unsigned char buf[KS_];
#pragma unroll
        for (int k = 0; k < KS_; ++k) {
            int tt = t + k;
            buf[k] = (tt < TP_) ? c[(size_t)tt * N_] : (unsigned char)0;
        }
        int adv = KS_;
#pragma unroll
        for (int k = 0; k < KS_; ++k) {
            if (buf[k]) {
                out[(((size_t)b * OC_ + (buf[k] - 1)) * N_ + n) * TP_ + (t + k)] = 1.0f;
                adv = k + KS_;
                break;
            }
        }
        t += adv;
    }
}

// ===========================================================================
extern "C" void kernel_launch(void* const* d_in, const int* in_sizes, int n_in,
                              void* d_out, int out_size, void* d_ws, size_t ws_size,
                              hipStream_t stream) {
    const float* x = (const float*)d_in[0];   // [16][1][64][512] binary
    const float* w = (const float*)d_in[1];   // [2560][64]
    float* out = (float*)d_out;               // [16][10][256][561]

    char* ws = (char*)d_ws;
    const size_t szA = (size_t)MPAD * KTOT;        //  27,721,728
    const size_t szB = (size_t)BROWS * KTOT;       //  23,592,960
    const size_t szP = (size_t)MVAL * O_ * 4;      //  91,914,240
    const size_t szC = (size_t)B_ * TP_ * N_;      //   2,297,856
    const size_t need = szA + szB + szP + szC;     // ~145.5 MB

    hipMemsetAsync(d_out, 0, (size_t)out_size * sizeof(float), stream);

    if (ws_size >= need) {
        unsigned char* Aim = (unsigned char*)ws;
        signed char* Bt    = (signed char*)(ws + szA);
        float* pot         = (float*)(ws + szA + szB);
        unsigned char* code = (unsigned char*)(ws + szA + szB + szP);

        prep_A8<<<(MPAD * KTOT / 4 + 255) / 256, 256, 0, stream>>>(x, Aim);
        prep_B8<<<(O_ * KTOT + 255) / 256, 256, 0, stream>>>(w, Bt);
        gemm_i8<<<dim3(NB, MPAD / 192), 256, 0, stream>>>(Aim, Bt, pot);
        scan_prep<<<(B_ * TP_ * N_ + 255) / 256, 256, 0, stream>>>(pot, code);
        scan_run<<<(B_ * N_ + 255) / 256, 256, 0, stream>>>(code, out);
    } else {
        // fallback: round-1 direct conv (needs ~95 MB)
        size_t pot_bytes  = (size_t)B_ * TP_ * O_ * sizeof(float);
        size_t code_bytes = (size_t)B_ * TP_ * N_;
        float* pot = (float*)ws;
        unsigned char* code = (unsigned char*)(ws + pot_bytes);
        float* wT = (float*)(ws + pot_bytes + code_bytes);

        transpose_w<<<(O_ * S_ + 255) / 256, 256, 0, stream>>>(w, wT);
        conv_kernel<<<dim3(O_ / 256, B_, (TP_ + TT - 1) / TT), 256, 0, stream>>>(x, wT, pot);
        scan_prep<<<(B_ * TP_ * N_ + 255) / 256, 256, 0, stream>>>(pot, code);
        scan_run<<<(B_ * N_ + 255) / 256, 256, 0, stream>>>(code, out);
    }
}